// Round 2
// baseline (354.919 us; speedup 1.0000x reference)
//
#include <hip/hip_runtime.h>
#include <stdint.h>

#pragma clang fp contract(off)

#define BS 32
#define NB 64
#define NA 8400
#define NC 80
#define TK 13

// ---------- CIoU, numpy op order, no FMA contraction ----------
__device__ __forceinline__ float ciou_f(float g0, float g1, float g2, float g3,
                                        float p0, float p1, float p2, float p3) {
    const float E = 1e-7f;
    float w1 = g2 - g0, h1 = (g3 - g1) + E;
    float w2 = p2 - p0, h2 = (p3 - p1) + E;
    float iw = fminf(g2, p2) - fmaxf(g0, p0); iw = fmaxf(iw, 0.f);
    float ih = fminf(g3, p3) - fmaxf(g1, p1); ih = fmaxf(ih, 0.f);
    float inter = iw * ih;
    float uni = w1 * h1 + w2 * h2 - inter + E;
    float iou = inter / uni;
    float cw = fmaxf(g2, p2) - fminf(g0, p0);
    float ch = fmaxf(g3, p3) - fminf(g1, p1);
    float c2 = cw * cw + ch * ch + E;
    float dx = p0 + p2 - g0 - g2;
    float dy = p1 + p3 - g1 - g3;
    float rho2 = (dx * dx + dy * dy) / 4.0f;
    float da = atanf(w2 / h2) - atanf(w1 / h1);
    float v = 0.4052847345693511f * (da * da);
    float alpha = v / ((v - iou) + 1.0000001f);
    return iou - (rho2 / c2 + v * alpha);
}

// align metric for one (gt row, anchor); also returns in_gts + masked overlap
__device__ __forceinline__ void cell_metrics(
    const float* __restrict__ pd_scores,
    const float* __restrict__ pd_bboxes,
    float ax, float ay, float g0, float g1, float g2, float g3,
    int b, int a, int lbl,
    float& align, float& ov, int& in_gts)
{
    float d0 = ax - g0, d1 = ay - g1, d2 = g2 - ax, d3 = g3 - ay;
    float dmin = fminf(fminf(d0, d1), fminf(d2, d3));
    align = 0.f; ov = 0.f; in_gts = 0;
    if (dmin > 1e-9f) {
        in_gts = 1;
        const float4 p = *(const float4*)&pd_bboxes[(b * NA + a) * 4];
        ov = fmaxf(ciou_f(g0, g1, g2, g3, p.x, p.y, p.z, p.w), 0.f);
        float sc = pd_scores[(b * NA + a) * NC + lbl];
        align = sc * powf(ov, 6.0f);
    }
}

// ================= K1: per (b,j) row -> exact top-13 of align metric =================
// tie-break identical to top_k / stable argsort: value desc, index asc.
__global__ __launch_bounds__(256) void k1_topk(
    const float* __restrict__ pd_scores,
    const float* __restrict__ pd_bboxes,
    const float* __restrict__ anc,
    const int* __restrict__ gt_labels,
    const float* __restrict__ gt_bboxes,
    const float* __restrict__ mask_gt,
    int* __restrict__ tk_a, float* __restrict__ tk_v,
    float* __restrict__ tk_o, int* __restrict__ tk_f)
{
    int r = blockIdx.x;              // b*NB + j
    int b = r >> 6;
    int tid = threadIdx.x;

    if (mask_gt[r] <= 0.f) {         // masked row contributes nothing downstream
        if (tid < TK) {
            tk_a[r * TK + tid] = 0; tk_v[r * TK + tid] = 0.f;
            tk_o[r * TK + tid] = 0.f; tk_f[r * TK + tid] = 0;
        }
        return;
    }
    float g0 = gt_bboxes[r * 4 + 0], g1 = gt_bboxes[r * 4 + 1];
    float g2 = gt_bboxes[r * 4 + 2], g3 = gt_bboxes[r * 4 + 3];
    int lbl = gt_labels[r];

    // per-thread top-13, sorted (val desc, idx asc)
    float val[TK]; int idx[TK];
#pragma unroll
    for (int k = 0; k < TK; k++) { val[k] = -1.f; idx[k] = 0x7fffffff; }

    for (int a = tid; a < NA; a += 256) {
        float ax = anc[2 * a], ay = anc[2 * a + 1];
        float align, ov; int ig;
        cell_metrics(pd_scores, pd_bboxes, ax, ay, g0, g1, g2, g3, b, a, lbl,
                     align, ov, ig);
        // within a thread, indices only increase, so an equal value can never
        // displace an earlier entry -> strict > against current 13th suffices
        if (align > val[TK - 1]) {
            float cv = align; int ci = a;
#pragma unroll
            for (int k = 0; k < TK; k++) {
                bool better = (cv > val[k]) || (cv == val[k] && ci < idx[k]);
                float tv = better ? cv : val[k]; int ti = better ? ci : idx[k];
                cv = better ? val[k] : cv;       ci = better ? idx[k] : ci;
                val[k] = tv; idx[k] = ti;
            }
        }
    }

    // block merge: 256x13 candidates in LDS, 13 selection rounds
    __shared__ float lv[256 * TK];
    __shared__ int   li[256 * TK];
    __shared__ float rv[256];
    __shared__ int   ri[256];
    __shared__ int   rp[256];
    __shared__ int   wa[TK];
    __shared__ float wv[TK];
#pragma unroll
    for (int k = 0; k < TK; k++) { lv[k * 256 + tid] = val[k]; li[k * 256 + tid] = idx[k]; }
    __syncthreads();

    for (int round = 0; round < TK; round++) {
        float bv = -2.f; int bi = 0x7fffffff; int bp = 0;
#pragma unroll
        for (int k = 0; k < TK; k++) {
            int p = k * 256 + tid;
            float v = lv[p]; int i = li[p];
            if (v > bv || (v == bv && i < bi)) { bv = v; bi = i; bp = p; }
        }
        rv[tid] = bv; ri[tid] = bi; rp[tid] = bp;
        __syncthreads();
        for (int s = 128; s > 0; s >>= 1) {
            if (tid < s) {
                float v2 = rv[tid + s]; int i2 = ri[tid + s];
                if (v2 > rv[tid] || (v2 == rv[tid] && i2 < ri[tid])) {
                    rv[tid] = v2; ri[tid] = i2; rp[tid] = rp[tid + s];
                }
            }
            __syncthreads();
        }
        if (tid == 0) {
            wa[round] = ri[0]; wv[round] = rv[0];
            lv[rp[0]] = -1.f; li[rp[0]] = 0x7fffffff;   // consume winner
        }
        __syncthreads();
    }

    // emit winners: recompute overlap + in_gts flag only at the 13 anchors
    if (tid < TK) {
        int a = wa[tid];
        float ax = anc[2 * a], ay = anc[2 * a + 1];
        float align, ov; int ig;
        cell_metrics(pd_scores, pd_bboxes, ax, ay, g0, g1, g2, g3, b, a, lbl,
                     align, ov, ig);
        tk_a[r * TK + tid] = a;
        tk_v[r * TK + tid] = wv[tid];
        tk_o[r * TK + tid] = ov;
        tk_f[r * TK + tid] = ig;     // mask_pos_pre = in_topk && in_gts && mgt
    }
}

// ================= K2a: init workspace =================
__global__ void k2a_init(int* cnt, int* jA, unsigned* posA, unsigned* posO) {
    int i = blockIdx.x * 256 + threadIdx.x;
    if (i < BS * NA) { cnt[i] = 0; jA[i] = -1; }
    if (i < BS * NB) { posA[i] = 0u; posO[i] = 0u; }
}

// ================= K2b: fg count per anchor =================
__global__ void k2b_count(const int* __restrict__ tk_a, const int* __restrict__ tk_f,
                          int* __restrict__ cnt) {
    int c = blockIdx.x * 256 + threadIdx.x;
    if (c >= BS * NB * TK) return;
    if (!tk_f[c]) return;
    int r = c / TK; int b = r >> 6;
    atomicAdd(&cnt[b * NA + tk_a[c]], 1);
}

// ================= K2c: unique-assignment anchors =================
__global__ void k2c_single(const int* __restrict__ tk_a, const float* __restrict__ tk_v,
                           const float* __restrict__ tk_o, const int* __restrict__ tk_f,
                           const int* __restrict__ cnt, int* __restrict__ jA,
                           float* __restrict__ av, float* __restrict__ ovv) {
    int c = blockIdx.x * 256 + threadIdx.x;
    if (c >= BS * NB * TK) return;
    if (!tk_f[c]) return;
    int r = c / TK; int b = r >> 6; int j = r & 63;
    int a = tk_a[c];
    int i = b * NA + a;
    if (cnt[i] == 1) { jA[i] = j; av[i] = tk_v[c]; ovv[i] = tk_o[c]; }
}

// ================= K2d: multi-assigned anchors -> argmax_j overlaps =================
__global__ void k2d_multi(
    const float* __restrict__ pd_scores,
    const float* __restrict__ pd_bboxes,
    const float* __restrict__ anc,
    const int* __restrict__ gt_labels,
    const float* __restrict__ gt_bboxes,
    const float* __restrict__ mask_gt,
    const int* __restrict__ cnt, int* __restrict__ jA,
    float* __restrict__ av, float* __restrict__ ovv)
{
    int i = blockIdx.x * 256 + threadIdx.x;
    if (i >= BS * NA) return;
    if (cnt[i] < 2) return;
    int b = i / NA, a = i - b * NA;
    float ax = anc[2 * a], ay = anc[2 * a + 1];

    float best = -1.f; int bj = 0;
    for (int j = 0; j < NB; j++) {
        float o = 0.f;
        if (mask_gt[b * NB + j] > 0.f) {
            const float4 g = *(const float4*)&gt_bboxes[(b * NB + j) * 4];
            float al, ov; int ig;
            cell_metrics(pd_scores, pd_bboxes, ax, ay, g.x, g.y, g.z, g.w, b, a,
                         0 /*label unused for ov*/, al, ov, ig);
            o = ov;
        }
        if (o > best) { best = o; bj = j; }   // argmax, first index wins ties
    }
    // align & overlap at (bj, a) with validity mask (matches align_metric*mask_pos)
    float alg = 0.f, o = 0.f;
    if (mask_gt[b * NB + bj] > 0.f) {
        const float4 g = *(const float4*)&gt_bboxes[(b * NB + bj) * 4];
        float al, ov2; int ig;
        cell_metrics(pd_scores, pd_bboxes, ax, ay, g.x, g.y, g.z, g.w, b, a,
                     gt_labels[b * NB + bj], al, ov2, ig);
        alg = al; o = ov2;
    }
    jA[i] = bj; av[i] = alg; ovv[i] = o;
}

// ================= K2e: pos_align / pos_over per gt row (float-bits atomicMax) ====
__global__ void k2e_pos(const int* __restrict__ jA, const float* __restrict__ av,
                        const float* __restrict__ ovv,
                        unsigned* __restrict__ posA, unsigned* __restrict__ posO) {
    int i = blockIdx.x * 256 + threadIdx.x;
    if (i >= BS * NA) return;
    int jj = jA[i]; if (jj < 0) return;
    int b = i / NA;
    atomicMax(&posA[b * NB + jj], __float_as_uint(av[i]));   // values >= 0
    atomicMax(&posO[b * NB + jj], __float_as_uint(ovv[i]));
}

// ================= K2f: per-anchor small outputs + norm/cls for K3 =================
__global__ void k2f_final(const int* __restrict__ gt_labels,
                          const float* __restrict__ gt_bboxes,
                          const int* __restrict__ jA, const float* __restrict__ av,
                          const unsigned* __restrict__ posA, const unsigned* __restrict__ posO,
                          float* __restrict__ out,
                          float* __restrict__ normw, int* __restrict__ clsw) {
    int i = blockIdx.x * 256 + threadIdx.x;
    if (i >= BS * NA) return;
    int b = i / NA;
    int jj = jA[i];
    int tg = jj < 0 ? 0 : jj;
    int lab = gt_labels[b * NB + tg]; lab = lab < 0 ? 0 : lab;

    float* o_lab  = out;                              // (bs,na)
    float* o_bbox = out + BS * NA;                    // (bs,na,4)
    float* o_fg   = out + BS * NA * (5 + NC);         // (bs,na) bool as float
    float* o_idx  = o_fg + BS * NA;                   // (bs,na)

    o_lab[i] = (float)lab;
    float4 bb = *(const float4*)&gt_bboxes[(b * NB + tg) * 4];  // exact passthrough
    *(float4*)&o_bbox[i * 4] = bb;
    o_fg[i] = (jj >= 0) ? 1.f : 0.f;
    o_idx[i] = (float)tg;

    float nrm = 0.f;
    if (jj >= 0) {
        float pa = __uint_as_float(posA[b * NB + jj]);
        float po = __uint_as_float(posO[b * NB + jj]);
        nrm = (av[i] * po) / (pa + 1e-9f);
    }
    normw[i] = nrm;
    clsw[i] = (jj >= 0) ? lab : -1;
}

// ================= K3: fill target_scores (one-hot * norm), 16B stores ============
__global__ void k3_scores(const float* __restrict__ normw, const int* __restrict__ clsw,
                          float* __restrict__ out) {
    int t = blockIdx.x * 256 + threadIdx.x;          // BS*NA*NC/4 = 5,376,000 exactly
    int row = t / 20;
    int c4 = (t - row * 20) * 4;
    int cls = clsw[row];
    float nv = normw[row];
    float4 v;
    v.x = (c4 + 0 == cls) ? nv : 0.f;
    v.y = (c4 + 1 == cls) ? nv : 0.f;
    v.z = (c4 + 2 == cls) ? nv : 0.f;
    v.w = (c4 + 3 == cls) ? nv : 0.f;
    float* o_sc = out + BS * NA * 5;
    *(float4*)&o_sc[row * NC + c4] = v;
}

extern "C" void kernel_launch(void* const* d_in, const int* in_sizes, int n_in,
                              void* d_out, int out_size, void* d_ws, size_t ws_size,
                              hipStream_t stream) {
    const float* pd_scores = (const float*)d_in[0];
    const float* pd_bboxes = (const float*)d_in[1];
    const float* anc       = (const float*)d_in[2];
    const int*   gt_labels = (const int*)d_in[3];
    const float* gt_bboxes = (const float*)d_in[4];
    const float* mask_gt   = (const float*)d_in[5];
    float* out = (float*)d_out;

    char* w = (char*)d_ws;
    const int NCAND = BS * NB * TK;      // 26624
    int*      tk_a = (int*)w;      w += NCAND * 4;
    int*      tk_f = (int*)w;      w += NCAND * 4;
    float*    tk_v = (float*)w;    w += NCAND * 4;
    float*    tk_o = (float*)w;    w += NCAND * 4;
    int*      cnt  = (int*)w;      w += BS * NA * 4;
    int*      jA   = (int*)w;      w += BS * NA * 4;
    float*    av   = (float*)w;    w += BS * NA * 4;
    float*    ovv  = (float*)w;    w += BS * NA * 4;
    unsigned* posA = (unsigned*)w; w += BS * NB * 4;
    unsigned* posO = (unsigned*)w; w += BS * NB * 4;
    float*    normw = (float*)w;   w += BS * NA * 4;
    int*      clsw  = (int*)w;     w += BS * NA * 4;

    k1_topk<<<BS * NB, 256, 0, stream>>>(pd_scores, pd_bboxes, anc, gt_labels,
                                         gt_bboxes, mask_gt, tk_a, tk_v, tk_o, tk_f);
    k2a_init<<<(BS * NA + 255) / 256, 256, 0, stream>>>(cnt, jA, posA, posO);
    k2b_count<<<(NCAND + 255) / 256, 256, 0, stream>>>(tk_a, tk_f, cnt);
    k2c_single<<<(NCAND + 255) / 256, 256, 0, stream>>>(tk_a, tk_v, tk_o, tk_f,
                                                        cnt, jA, av, ovv);
    k2d_multi<<<(BS * NA + 255) / 256, 256, 0, stream>>>(pd_scores, pd_bboxes, anc,
                                                         gt_labels, gt_bboxes, mask_gt,
                                                         cnt, jA, av, ovv);
    k2e_pos<<<(BS * NA + 255) / 256, 256, 0, stream>>>(jA, av, ovv, posA, posO);
    k2f_final<<<(BS * NA + 255) / 256, 256, 0, stream>>>(gt_labels, gt_bboxes, jA, av,
                                                         posA, posO, out, normw, clsw);
    k3_scores<<<(BS * NA * NC / 4 + 255) / 256, 256, 0, stream>>>(normw, clsw, out);
}

// Round 3
// 223.519 us; speedup vs baseline: 1.5879x; 1.5879x over previous
//
#include <hip/hip_runtime.h>
#include <stdint.h>

#pragma clang fp contract(off)

#define BS 32
#define NB 64
#define NA 8400
#define NC 80
#define TK 13
#define QMAX 1024
#define FORCED 32

// ---------- CIoU, numpy op order, no FMA contraction ----------
__device__ __forceinline__ float ciou_f(float g0, float g1, float g2, float g3,
                                        float p0, float p1, float p2, float p3) {
    const float E = 1e-7f;
    float w1 = g2 - g0, h1 = (g3 - g1) + E;
    float w2 = p2 - p0, h2 = (p3 - p1) + E;
    float iw = fminf(g2, p2) - fmaxf(g0, p0); iw = fmaxf(iw, 0.f);
    float ih = fminf(g3, p3) - fmaxf(g1, p1); ih = fmaxf(ih, 0.f);
    float inter = iw * ih;
    float uni = w1 * h1 + w2 * h2 - inter + E;
    float iou = inter / uni;
    float cw = fmaxf(g2, p2) - fminf(g0, p0);
    float ch = fmaxf(g3, p3) - fminf(g1, p1);
    float c2 = cw * cw + ch * ch + E;
    float dx = p0 + p2 - g0 - g2;
    float dy = p1 + p3 - g1 - g3;
    float rho2 = (dx * dx + dy * dy) / 4.0f;
    float da = atanf(w2 / h2) - atanf(w1 / h1);
    float v = 0.4052847345693511f * (da * da);
    float alpha = v / ((v - iou) + 1.0000001f);
    return iou - (rho2 / c2 + v * alpha);
}

// ================= K1: compact in-box anchors, then dense metrics, then top-13 ======
// Candidate set = {in-box anchors} U {anchors 0..31}. Proof of sufficiency for the
// reference's zero-padding tie-break: zeros are picked only when npos<13; then
// positives among idx 0..31 < 13, so >=19 zero candidates with idx<32 exist, and the
// reference's picked zeros (lowest-index zeros globally) all have idx<32.
__global__ __launch_bounds__(256) void k1_topk(
    const float* __restrict__ pd_scores,
    const float* __restrict__ pd_bboxes,
    const float* __restrict__ anc,
    const int* __restrict__ gt_labels,
    const float* __restrict__ gt_bboxes,
    const float* __restrict__ mask_gt,
    int* __restrict__ tk_a, float* __restrict__ tk_v,
    float* __restrict__ tk_o, int* __restrict__ tk_f)
{
    int r = blockIdx.x;              // b*NB + j
    int b = r >> 6;
    int tid = threadIdx.x;

    if (mask_gt[r] <= 0.f) {         // masked row contributes nothing downstream
        if (tid < TK) {
            tk_a[r * TK + tid] = 0; tk_v[r * TK + tid] = 0.f;
            tk_o[r * TK + tid] = 0.f; tk_f[r * TK + tid] = 0;
        }
        return;
    }

    __shared__ int   qn;
    __shared__ int   qa[QMAX];       // bit30 = in-box flag, low bits = anchor idx
    __shared__ float qv[QMAX];
    __shared__ float qo[QMAX];

    float4 g = *(const float4*)&gt_bboxes[r * 4];
    int lbl = gt_labels[r];
    if (tid == 0) qn = 0;
    __syncthreads();

    // Phase A: cheap in-box scan + compaction (no divergent heavy math)
    for (int a = tid; a < NA; a += 256) {
        float2 ap = *(const float2*)&anc[2 * a];
        float d0 = ap.x - g.x, d1 = ap.y - g.y, d2 = g.z - ap.x, d3 = g.w - ap.y;
        float dmin = fminf(fminf(d0, d1), fminf(d2, d3));
        bool in = dmin > 1e-9f;
        if (in || a < FORCED) {
            int p = atomicAdd(&qn, 1);
            if (p < QMAX) qa[p] = a | (in ? (1 << 30) : 0);
        }
    }
    __syncthreads();
    int n = min(qn, QMAX);           // always >= FORCED

    // Phase B: dense CIoU + align over compacted candidates (all lanes active)
    for (int c = tid; c < n; c += 256) {
        int packed = qa[c]; int a = packed & 0x3fffffff; bool in = (packed >> 30) & 1;
        float align = 0.f, ov = 0.f;
        if (in) {
            float4 p = *(const float4*)&pd_bboxes[(b * NA + a) * 4];
            ov = fmaxf(ciou_f(g.x, g.y, g.z, g.w, p.x, p.y, p.z, p.w), 0.f);
            float sc = pd_scores[(b * NA + a) * NC + lbl];
            float o2 = ov * ov;
            align = sc * (o2 * o2 * o2);
        }
        qv[c] = align; qo[c] = ov;
    }
    __syncthreads();

    // Phase C: top-13 by wave 0, shuffle argmax, zero barriers.
    // tie-break identical to top_k / stable argsort: value desc, global index asc.
    if (tid < 64) {
        int lane = tid;
        unsigned consumed = 0;       // per-lane bitmask over its strided slots (<=16)
        int wslot = 0; float wval = 0.f;
        for (int round = 0; round < TK; round++) {
            float bv = -2.f; int bgi = 0x7fffffff; int bsl = 0;
            int li = 0;
            for (int c = lane; c < n; c += 64, li++) {
                if (consumed & (1u << li)) continue;
                float v = qv[c]; int gi = qa[c] & 0x3fffffff;
                if (v > bv || (v == bv && gi < bgi)) { bv = v; bgi = gi; bsl = c; }
            }
            for (int off = 32; off; off >>= 1) {
                float v2 = __shfl_down(bv, off);
                int  gi2 = __shfl_down(bgi, off);
                int  sl2 = __shfl_down(bsl, off);
                if (v2 > bv || (v2 == bv && gi2 < bgi)) { bv = v2; bgi = gi2; bsl = sl2; }
            }
            int wsl = __shfl(bsl, 0);
            float wv = __shfl(bv, 0);
            if ((wsl & 63) == lane) consumed |= 1u << (wsl >> 6);
            if (lane == round) { wslot = wsl; wval = wv; }
        }
        if (lane < TK) {
            int packed = qa[wslot]; int a = packed & 0x3fffffff; int in = (packed >> 30) & 1;
            tk_a[r * TK + lane] = a;
            tk_v[r * TK + lane] = wval;
            tk_o[r * TK + lane] = qo[wslot];
            tk_f[r * TK + lane] = in;   // mask_pos_pre = in_topk && in_gts && mgt
        }
    }
}

// ================= K2a: init workspace =================
__global__ void k2a_init(int* cnt, int* jA, unsigned* posA, unsigned* posO, int* mcount) {
    int i = blockIdx.x * 256 + threadIdx.x;
    if (i < BS * NA) { cnt[i] = 0; jA[i] = -1; }
    if (i < BS * NB) { posA[i] = 0u; posO[i] = 0u; }
    if (i == 0) *mcount = 0;
}

// ================= K2b: fg count per anchor =================
__global__ void k2b_count(const int* __restrict__ tk_a, const int* __restrict__ tk_f,
                          int* __restrict__ cnt) {
    int c = blockIdx.x * 256 + threadIdx.x;
    if (c >= BS * NB * TK) return;
    if (!tk_f[c]) return;
    int r = c / TK; int b = r >> 6;
    atomicAdd(&cnt[b * NA + tk_a[c]], 1);
}

// ========== K2c: singles assigned + pos maxes; multi anchors claimed into list =====
__global__ void k2c_single(const int* __restrict__ tk_a, const float* __restrict__ tk_v,
                           const float* __restrict__ tk_o, const int* __restrict__ tk_f,
                           const int* __restrict__ cnt, int* __restrict__ jA,
                           float* __restrict__ av,
                           unsigned* __restrict__ posA, unsigned* __restrict__ posO,
                           int* __restrict__ mlist, int* __restrict__ mcount) {
    int c = blockIdx.x * 256 + threadIdx.x;
    if (c >= BS * NB * TK) return;
    if (!tk_f[c]) return;
    int r = c / TK; int b = r >> 6; int j = r & 63;
    int a = tk_a[c];
    int i = b * NA + a;
    if (cnt[i] == 1) {
        jA[i] = j; av[i] = tk_v[c];
        atomicMax(&posA[b * NB + j], __float_as_uint(tk_v[c]));   // values >= 0
        atomicMax(&posO[b * NB + j], __float_as_uint(tk_o[c]));
    } else {
        int old = atomicCAS(&jA[i], -1, -2);
        if (old == -1) { int p = atomicAdd(mcount, 1); mlist[p] = i; }
    }
}

// ========== K2d: multi anchors, one wave per anchor, lanes = 64 gt rows ============
__global__ __launch_bounds__(256) void k2d_multi(
    const float* __restrict__ pd_scores,
    const float* __restrict__ pd_bboxes,
    const float* __restrict__ anc,
    const int* __restrict__ gt_labels,
    const float* __restrict__ gt_bboxes,
    const float* __restrict__ mask_gt,
    const int* __restrict__ mlist, const int* __restrict__ mcount,
    int* __restrict__ jA, float* __restrict__ av,
    unsigned* __restrict__ posA, unsigned* __restrict__ posO)
{
    int wid = (blockIdx.x * 256 + threadIdx.x) >> 6;
    int lane = threadIdx.x & 63;
    int nwaves = (gridDim.x * 256) >> 6;
    int nm = *mcount;
    for (int e = wid; e < nm; e += nwaves) {
        int i = mlist[e];
        int b = i / NA, a = i - b * NA;
        float2 ap = *(const float2*)&anc[2 * a];
        int row = b * NB + lane;
        float o = 0.f;
        if (mask_gt[row] > 0.f) {
            float4 g = *(const float4*)&gt_bboxes[row * 4];
            float d0 = ap.x - g.x, d1 = ap.y - g.y, d2 = g.z - ap.x, d3 = g.w - ap.y;
            float dmin = fminf(fminf(d0, d1), fminf(d2, d3));
            if (dmin > 1e-9f) {
                float4 p = *(const float4*)&pd_bboxes[(b * NA + a) * 4];
                o = fmaxf(ciou_f(g.x, g.y, g.z, g.w, p.x, p.y, p.z, p.w), 0.f);
            }
        }
        float bv = o; int bj = lane;                   // argmax, lowest j wins ties
        for (int off = 32; off; off >>= 1) {
            float v2 = __shfl_down(bv, off);
            int  j2 = __shfl_down(bj, off);
            if (v2 > bv || (v2 == bv && j2 < bj)) { bv = v2; bj = j2; }
        }
        if (lane == 0) {
            int lbl = gt_labels[b * NB + bj];
            float sc = pd_scores[(b * NA + a) * NC + lbl];
            float o2 = bv * bv;
            float alg = sc * (o2 * o2 * o2);           // masked ov=0 -> alg=0
            jA[i] = bj; av[i] = alg;
            atomicMax(&posA[b * NB + bj], __float_as_uint(alg));
            atomicMax(&posO[b * NB + bj], __float_as_uint(bv));
        }
    }
}

// ================= K2f: per-anchor small outputs + norm/cls for K3 =================
__global__ void k2f_final(const int* __restrict__ gt_labels,
                          const float* __restrict__ gt_bboxes,
                          const int* __restrict__ jA, const float* __restrict__ av,
                          const unsigned* __restrict__ posA, const unsigned* __restrict__ posO,
                          float* __restrict__ out,
                          float* __restrict__ normw, int* __restrict__ clsw) {
    int i = blockIdx.x * 256 + threadIdx.x;
    if (i >= BS * NA) return;
    int b = i / NA;
    int jj = jA[i];
    int tg = jj < 0 ? 0 : jj;
    int lab = gt_labels[b * NB + tg]; lab = lab < 0 ? 0 : lab;

    float* o_lab  = out;                              // (bs,na)
    float* o_bbox = out + BS * NA;                    // (bs,na,4)
    float* o_fg   = out + BS * NA * (5 + NC);         // (bs,na) bool as float
    float* o_idx  = o_fg + BS * NA;                   // (bs,na)

    o_lab[i] = (float)lab;
    float4 bb = *(const float4*)&gt_bboxes[(b * NB + tg) * 4];  // exact passthrough
    *(float4*)&o_bbox[i * 4] = bb;
    o_fg[i] = (jj >= 0) ? 1.f : 0.f;
    o_idx[i] = (float)tg;

    float nrm = 0.f;
    if (jj >= 0) {
        float pa = __uint_as_float(posA[b * NB + jj]);
        float po = __uint_as_float(posO[b * NB + jj]);
        nrm = (av[i] * po) / (pa + 1e-9f);
    }
    normw[i] = nrm;
    clsw[i] = (jj >= 0) ? lab : -1;
}

// ================= K3: fill target_scores (one-hot * norm), 16B stores ============
__global__ void k3_scores(const float* __restrict__ normw, const int* __restrict__ clsw,
                          float* __restrict__ out) {
    int t = blockIdx.x * 256 + threadIdx.x;          // BS*NA*NC/4 = 5,376,000 exactly
    int row = t / 20;
    int c4 = (t - row * 20) * 4;
    int cls = clsw[row];
    float nv = normw[row];
    float4 v;
    v.x = (c4 + 0 == cls) ? nv : 0.f;
    v.y = (c4 + 1 == cls) ? nv : 0.f;
    v.z = (c4 + 2 == cls) ? nv : 0.f;
    v.w = (c4 + 3 == cls) ? nv : 0.f;
    float* o_sc = out + BS * NA * 5;
    *(float4*)&o_sc[row * NC + c4] = v;
}

extern "C" void kernel_launch(void* const* d_in, const int* in_sizes, int n_in,
                              void* d_out, int out_size, void* d_ws, size_t ws_size,
                              hipStream_t stream) {
    const float* pd_scores = (const float*)d_in[0];
    const float* pd_bboxes = (const float*)d_in[1];
    const float* anc       = (const float*)d_in[2];
    const int*   gt_labels = (const int*)d_in[3];
    const float* gt_bboxes = (const float*)d_in[4];
    const float* mask_gt   = (const float*)d_in[5];
    float* out = (float*)d_out;

    char* w = (char*)d_ws;
    const int NCAND = BS * NB * TK;      // 26624
    int*      tk_a = (int*)w;      w += NCAND * 4;
    int*      tk_f = (int*)w;      w += NCAND * 4;
    float*    tk_v = (float*)w;    w += NCAND * 4;
    float*    tk_o = (float*)w;    w += NCAND * 4;
    int*      cnt  = (int*)w;      w += BS * NA * 4;
    int*      jA   = (int*)w;      w += BS * NA * 4;
    float*    av   = (float*)w;    w += BS * NA * 4;
    unsigned* posA = (unsigned*)w; w += BS * NB * 4;
    unsigned* posO = (unsigned*)w; w += BS * NB * 4;
    float*    normw = (float*)w;   w += BS * NA * 4;
    int*      clsw  = (int*)w;     w += BS * NA * 4;
    int*      mlist = (int*)w;     w += NCAND * 4;
    int*      mcount = (int*)w;    w += 4;

    k2a_init<<<(BS * NA + 255) / 256, 256, 0, stream>>>(cnt, jA, posA, posO, mcount);
    k1_topk<<<BS * NB, 256, 0, stream>>>(pd_scores, pd_bboxes, anc, gt_labels,
                                         gt_bboxes, mask_gt, tk_a, tk_v, tk_o, tk_f);
    k2b_count<<<(NCAND + 255) / 256, 256, 0, stream>>>(tk_a, tk_f, cnt);
    k2c_single<<<(NCAND + 255) / 256, 256, 0, stream>>>(tk_a, tk_v, tk_o, tk_f,
                                                        cnt, jA, av, posA, posO,
                                                        mlist, mcount);
    k2d_multi<<<52, 256, 0, stream>>>(pd_scores, pd_bboxes, anc, gt_labels,
                                      gt_bboxes, mask_gt, mlist, mcount,
                                      jA, av, posA, posO);
    k2f_final<<<(BS * NA + 255) / 256, 256, 0, stream>>>(gt_labels, gt_bboxes, jA, av,
                                                         posA, posO, out, normw, clsw);
    k3_scores<<<(BS * NA * NC / 4 + 255) / 256, 256, 0, stream>>>(normw, clsw, out);
}